// Round 5
// baseline (7658.181 us; speedup 1.0000x reference)
//
#include <hip/hip_runtime.h>
#include <cstdint>
#include <cstddef>

#define HID 64
#define RPW 4   // batch rows per wave; one wave per block

// Exact-erf GELU via Abramowitz & Stegun 7.1.26 (max |erf err| ~1.5e-7).
__device__ __forceinline__ float fast_gelu(float z) {
    float u = z * 0.70710678118654752f;
    float a = __builtin_fabsf(u);
    float t = __builtin_amdgcn_rcpf(__builtin_fmaf(0.3275911f, a, 1.0f));
    float e = __builtin_amdgcn_exp2f((u * u) * -1.44269504088896f);   // exp(-u^2)
    float p =                   1.061405429f;
    p = __builtin_fmaf(p, t, -1.453152027f);
    p = __builtin_fmaf(p, t,  1.421413741f);
    p = __builtin_fmaf(p, t, -0.284496736f);
    p = __builtin_fmaf(p, t,  0.254829592f);
    p = p * t;
    float er = __builtin_fmaf(-p, e, 1.0f);     // erf(|u|)
    er = __builtin_copysignf(er, u);
    float zh = 0.5f * z;
    return __builtin_fmaf(zh, er, zh);
}

// 64 weights as named scalar locals, pinned into VGPRs. Lane j holds W_s[:, j].
#define DW4(a,b,c,d) \
    float w##a = W_s[(a)*HID + lane]; float w##b = W_s[(b)*HID + lane]; \
    float w##c = W_s[(c)*HID + lane]; float w##d = W_s[(d)*HID + lane];
#define PW4(a,b,c,d) \
    asm volatile("" : "+v"(w##a)); asm volatile("" : "+v"(w##b)); \
    asm volatile("" : "+v"(w##c)); asm volatile("" : "+v"(w##d));

// One uniform-address ds_read_b128 at slot j delivers h[j] for ALL 4 rows,
// paired with the single weight register w_j. p selects even/odd accumulator.
#define BJ(j, p) { \
    float4 hv = rb4[j]; \
    aA##p = __builtin_fmaf(hv.x, w##j, aA##p); \
    aB##p = __builtin_fmaf(hv.y, w##j, aB##p); \
    aC##p = __builtin_fmaf(hv.z, w##j, aC##p); \
    aD##p = __builtin_fmaf(hv.w, w##j, aD##p); }
#define B2(a, b) BJ(a, 0) BJ(b, 1)

// One 4-row recurrence step: read interleaved h from RB, write new h to WB.
#define STEP4(RB, WB, X0, X1, X2, X3) { \
    const float4* rb4 = reinterpret_cast<const float4*>(RB); \
    float aA0 = 0.f, aA1 = 0.f, aB0 = 0.f, aB1 = 0.f; \
    float aC0 = 0.f, aC1 = 0.f, aD0 = 0.f, aD1 = 0.f; \
    B2( 0, 1) B2( 2, 3) B2( 4, 5) B2( 6, 7) B2( 8, 9) B2(10,11) B2(12,13) B2(14,15) \
    B2(16,17) B2(18,19) B2(20,21) B2(22,23) B2(24,25) B2(26,27) B2(28,29) B2(30,31) \
    B2(32,33) B2(34,35) B2(36,37) B2(38,39) B2(40,41) B2(42,43) B2(44,45) B2(46,47) \
    B2(48,49) B2(50,51) B2(52,53) B2(54,55) B2(56,57) B2(58,59) B2(60,61) B2(62,63) \
    float zA = (aA0 + aA1) + __builtin_fmaf((X0), win, cb); \
    float zB = (aB0 + aB1) + __builtin_fmaf((X1), win, cb); \
    float zC = (aC0 + aC1) + __builtin_fmaf((X2), win, cb); \
    float zD = (aD0 + aD1) + __builtin_fmaf((X3), win, cb); \
    hA = fast_gelu(zA); hB = fast_gelu(zB); \
    hC = fast_gelu(zC); hD = fast_gelu(zD); \
    float4 st; st.x = hA; st.y = hB; st.z = hC; st.w = hD; \
    *reinterpret_cast<float4*>((WB) + 4 * lane) = st; }   /* ds_write_b128 */

#define RDL(v, k) __int_as_float(__builtin_amdgcn_readlane(__float_as_int(v), (k)))

__global__ __launch_bounds__(64, 1)
void ssm_kernel(const float* __restrict__ x,
                const float* __restrict__ W_in,
                const float* __restrict__ b_in,
                const float* __restrict__ W_s,
                const float* __restrict__ b_s,
                const float* __restrict__ W_out,
                const float* __restrict__ b_out,
                float* __restrict__ out,
                int B, int T) {
    // Ping-pong interleaved h: slot 4j+r = row r's h[j]. Wave-private.
    __shared__ float hbuf[2][RPW * HID];

    const int lane = threadIdx.x & 63;
    const int bA   = blockIdx.x * RPW;
    if (bA >= B) return;

    DW4( 0, 1, 2, 3)  DW4( 4, 5, 6, 7)  DW4( 8, 9,10,11)  DW4(12,13,14,15)
    DW4(16,17,18,19)  DW4(20,21,22,23)  DW4(24,25,26,27)  DW4(28,29,30,31)
    DW4(32,33,34,35)  DW4(36,37,38,39)  DW4(40,41,42,43)  DW4(44,45,46,47)
    DW4(48,49,50,51)  DW4(52,53,54,55)  DW4(56,57,58,59)  DW4(60,61,62,63)
    PW4( 0, 1, 2, 3)  PW4( 4, 5, 6, 7)  PW4( 8, 9,10,11)  PW4(12,13,14,15)
    PW4(16,17,18,19)  PW4(20,21,22,23)  PW4(24,25,26,27)  PW4(28,29,30,31)
    PW4(32,33,34,35)  PW4(36,37,38,39)  PW4(40,41,42,43)  PW4(44,45,46,47)
    PW4(48,49,50,51)  PW4(52,53,54,55)  PW4(56,57,58,59)  PW4(60,61,62,63)

    const float win = W_in[lane];
    const float cb  = b_in[lane] + b_s[lane];
    const float wo  = W_out[lane];
    const float bo  = b_out[0];

    float* buf0 = hbuf[0];
    float* buf1 = hbuf[1];
    {   // h0 = 0 for all 4 rows
        float4 z4; z4.x = 0.f; z4.y = 0.f; z4.z = 0.f; z4.w = 0.f;
        *reinterpret_cast<float4*>(buf0 + 4 * lane) = z4;
    }

    const size_t xb0 = (size_t)(bA + 0) * (size_t)T;
    const size_t xb1 = (size_t)(bA + 1) * (size_t)T;
    const size_t xb2 = (size_t)(bA + 2) * (size_t)T;
    const size_t xb3 = (size_t)(bA + 3) * (size_t)T;
    const int nch = T >> 6;            // T multiple of 64 (8192 here)

    float xv0 = x[xb0 + lane];         // chunk 0, coalesced per row
    float xv1 = x[xb1 + lane];
    float xv2 = x[xb2 + lane];
    float xv3 = x[xb3 + lane];
    float hA = 0.f, hB = 0.f, hC = 0.f, hD = 0.f;

    for (int tc = 0; tc < nch; ++tc) {
        int tn = (tc + 1) << 6;
        if (tn >= T) tn = 0;           // clamped prefetch; stale value unused
        float xn0 = x[xb0 + (size_t)tn + lane];
        float xn1 = x[xb1 + (size_t)tn + lane];
        float xn2 = x[xb2 + (size_t)tn + lane];
        float xn3 = x[xb3 + (size_t)tn + lane];

#pragma unroll 1
        for (int k = 0; k < 64; k += 2) {
            STEP4(buf0, buf1, RDL(xv0, k), RDL(xv1, k), RDL(xv2, k), RDL(xv3, k));
            STEP4(buf1, buf0, RDL(xv0, k + 1), RDL(xv1, k + 1),
                              RDL(xv2, k + 1), RDL(xv3, k + 1));
        }
        xv0 = xn0; xv1 = xn1; xv2 = xn2; xv3 = xn3;
    }

    // out[b] = h . W_out + b_out for each of the 4 rows
    float vA = hA * wo, vB = hB * wo, vC = hC * wo, vD = hD * wo;
#pragma unroll
    for (int m = 32; m >= 1; m >>= 1) {
        vA += __shfl_xor(vA, m, 64);
        vB += __shfl_xor(vB, m, 64);
        vC += __shfl_xor(vC, m, 64);
        vD += __shfl_xor(vD, m, 64);
    }
    if (lane == 0) {
        out[bA + 0] = vA + bo;
        out[bA + 1] = vB + bo;
        out[bA + 2] = vC + bo;
        out[bA + 3] = vD + bo;
    }
}

extern "C" void kernel_launch(void* const* d_in, const int* in_sizes, int n_in,
                              void* d_out, int out_size, void* d_ws, size_t ws_size,
                              hipStream_t stream) {
    const float* x     = (const float*)d_in[0];
    const float* W_in  = (const float*)d_in[1];
    const float* b_in  = (const float*)d_in[2];
    const float* W_s   = (const float*)d_in[3];
    const float* b_s   = (const float*)d_in[4];
    const float* W_out = (const float*)d_in[5];
    const float* b_out = (const float*)d_in[6];
    float* out = (float*)d_out;

    const int B = out_size;                 // [B,1] output
    const int T = in_sizes[0] / B;          // x is [B,T,1]

    const int blocks = (B + RPW - 1) / RPW;   // 1024 for B=4096
    ssm_kernel<<<blocks, 64, 0, stream>>>(
        x, W_in, b_in, W_s, b_s, W_out, b_out, out, B, T);
}

// Round 6
// 3147.234 us; speedup vs baseline: 2.4333x; 2.4333x over previous
//
#include <hip/hip_runtime.h>
#include <cstdint>
#include <cstddef>

#define HID 64
#define RPG 16          // batch rows per block = one MFMA M-tile
#define HSTR 72         // ushorts per h-plane row: 144 B (16B-aligned, bank-spread)

typedef short bf16x8 __attribute__((ext_vector_type(8)));
typedef float f32x4 __attribute__((ext_vector_type(4)));

// Exact-erf GELU via Abramowitz & Stegun 7.1.26 (max |erf err| ~1.5e-7).
__device__ __forceinline__ float fast_gelu(float z) {
    float u = z * 0.70710678118654752f;
    float a = __builtin_fabsf(u);
    float t = __builtin_amdgcn_rcpf(__builtin_fmaf(0.3275911f, a, 1.0f));
    float e = __builtin_amdgcn_exp2f((u * u) * -1.44269504088896f);   // exp(-u^2)
    float p =                   1.061405429f;
    p = __builtin_fmaf(p, t, -1.453152027f);
    p = __builtin_fmaf(p, t,  1.421413741f);
    p = __builtin_fmaf(p, t, -0.284496736f);
    p = __builtin_fmaf(p, t,  0.254829592f);
    p = p * t;
    float er = __builtin_fmaf(-p, e, 1.0f);
    er = __builtin_copysignf(er, u);
    float zh = 0.5f * z;
    return __builtin_fmaf(zh, er, zh);
}

__device__ __forceinline__ ushort bf16_hi(float f) {
    return (ushort)(__float_as_uint(f) >> 16);     // truncation: lo-plane captures residual
}
__device__ __forceinline__ float bf16_f(ushort u) {
    return __uint_as_float(((unsigned)u) << 16);
}

__global__ __launch_bounds__(256, 1)
void ssm_kernel(const float* __restrict__ x,
                const float* __restrict__ W_in,
                const float* __restrict__ b_in,
                const float* __restrict__ W_s,
                const float* __restrict__ b_s,
                const float* __restrict__ W_out,
                const float* __restrict__ b_out,
                float* __restrict__ out,
                int B, int T) {
    // h state as split-bf16 planes, ping-pong: hlds[pp][hi/lo][row*HSTR + col]
    __shared__ ushort hlds[2][2][RPG * HSTR];
    __shared__ float  xlds[64][RPG];               // x[t_local][row]

    const int tid  = threadIdx.x;
    const int wv   = tid >> 6;        // wave 0..3: owns output cols [16wv,16wv+16)
    const int lane = tid & 63;
    const int q    = lane >> 4;       // lane quartet index
    const int rr   = lane & 15;
    const int bA   = blockIdx.x * RPG;
    const int c    = (wv << 4) | rr;  // this lane's output column (0..63)

    // --- B fragments (weights, loaded once): B[k][c], k = 32*half + 8*q + e ---
    // Split hi/lo bf16. Any error in the assumed lane->k map cancels because the
    // A fragments below are built with the SAME map (sum over k is map-invariant).
    bf16x8 Bhi[2], Blo[2];
#pragma unroll
    for (int half = 0; half < 2; ++half) {
#pragma unroll
        for (int e = 0; e < 8; ++e) {
            const int k = half * 32 + q * 8 + e;
            const float wf = W_s[k * HID + c];
            const ushort hi = bf16_hi(wf);
            const float lof = wf - bf16_f(hi);
            Bhi[half][e] = (short)hi;
            Blo[half][e] = (short)bf16_hi(lof);
        }
    }

    const float win = W_in[c];
    const float cb  = b_in[c] + b_s[c];

    // zero h(pp=0)
    {
        ushort* p = &hlds[0][0][0];
        for (int i = tid; i < 2 * RPG * HSTR; i += 256) p[i] = 0;
    }

    const int nch = T >> 6;           // T multiple of 64 (8192 here)
    int pp = 0;

    for (int tc = 0; tc < nch; ++tc) {
        // Stage x[*, tc*64 .. +64) into xlds[t][row]; wave wv covers t in [16wv,16wv+16).
        // Rows of x are contiguous in t; the 4 waves of this block collectively touch
        // full cache lines, so HBM sees coalesced traffic via L1.
        {
            const int t4 = (wv << 4) + (q << 2);
            const float4 xg = *reinterpret_cast<const float4*>(
                &x[(size_t)(bA + rr) * (size_t)T + (size_t)(tc * 64 + t4)]);
            xlds[t4 + 0][rr] = xg.x;
            xlds[t4 + 1][rr] = xg.y;
            xlds[t4 + 2][rr] = xg.z;
            xlds[t4 + 3][rr] = xg.w;
        }
        __syncthreads();

#pragma unroll 2
        for (int tl = 0; tl < 64; ++tl) {
            const int np = pp ^ 1;
            // x for this lane's 4 C-rows (rows 4q..4q+3 match C-layout row=(lane>>4)*4+reg)
            const f32x4 xr = *reinterpret_cast<const f32x4*>(&xlds[tl][q << 2]);
            f32x4 acc1;
#pragma unroll
            for (int e = 0; e < 4; ++e) acc1[e] = __builtin_fmaf(xr[e], win, cb);
            f32x4 acc2 = {0.f, 0.f, 0.f, 0.f};

            // A fragments: row = lane&15, k = 32*half + 8*q + e  (same map as B)
            const ushort* hp = &hlds[pp][0][0];
            const ushort* lp = &hlds[pp][1][0];
            const int aoff = rr * HSTR + (q << 3);
            const bf16x8 Ahi0 = *reinterpret_cast<const bf16x8*>(hp + aoff);
            const bf16x8 Ahi1 = *reinterpret_cast<const bf16x8*>(hp + aoff + 32);
            const bf16x8 Alo0 = *reinterpret_cast<const bf16x8*>(lp + aoff);
            const bf16x8 Alo1 = *reinterpret_cast<const bf16x8*>(lp + aoff + 32);

            // hi@hi (chain 1) + hi@lo + lo@hi (chain 2); lo@lo dropped (~1e-6)
            acc1 = __builtin_amdgcn_mfma_f32_16x16x32_bf16(Ahi0, Bhi[0], acc1, 0, 0, 0);
            acc1 = __builtin_amdgcn_mfma_f32_16x16x32_bf16(Ahi1, Bhi[1], acc1, 0, 0, 0);
            acc2 = __builtin_amdgcn_mfma_f32_16x16x32_bf16(Ahi0, Blo[0], acc2, 0, 0, 0);
            acc2 = __builtin_amdgcn_mfma_f32_16x16x32_bf16(Ahi1, Blo[1], acc2, 0, 0, 0);
            acc2 = __builtin_amdgcn_mfma_f32_16x16x32_bf16(Alo0, Bhi[0], acc2, 0, 0, 0);
            acc2 = __builtin_amdgcn_mfma_f32_16x16x32_bf16(Alo1, Bhi[1], acc2, 0, 0, 0);

            // GELU + split + write: C row = 4q+e, col = c (verified C/D layout)
            ushort* whp = &hlds[np][0][0];
            ushort* wlp = &hlds[np][1][0];
#pragma unroll
            for (int e = 0; e < 4; ++e) {
                const float z = acc1[e] + acc2[e];
                const float h = fast_gelu(z);
                const unsigned hb = __float_as_uint(h);
                const float lof = h - __uint_as_float(hb & 0xffff0000u);
                const int widx = ((q << 2) + e) * HSTR + c;
                whp[widx] = (ushort)(hb >> 16);
                wlp[widx] = bf16_hi(lof);
            }
            __syncthreads();
            pp ^= 1;
        }
    }

    // Epilogue: out[b] = h_T . W_out + b_out. Wave wv handles rows 4wv+q? No:
    // wave wv covers rows {4wv..4wv+3} via q; lane rr covers col-quad rr*4.
    {
        const int row = (wv << 2) + q;
        const int c4  = rr << 2;
        const ushort* hp = &hlds[pp][0][row * HSTR + c4];
        const ushort* lp = &hlds[pp][1][row * HSTR + c4];
        float s = 0.f;
#pragma unroll
        for (int j = 0; j < 4; ++j) {
            const float hv = bf16_f(hp[j]) + bf16_f(lp[j]);
            s = __builtin_fmaf(hv, W_out[c4 + j], s);
        }
        s += __shfl_xor(s, 1, 64);
        s += __shfl_xor(s, 2, 64);
        s += __shfl_xor(s, 4, 64);
        s += __shfl_xor(s, 8, 64);
        if (rr == 0) out[bA + row] = s + b_out[0];
    }
}

extern "C" void kernel_launch(void* const* d_in, const int* in_sizes, int n_in,
                              void* d_out, int out_size, void* d_ws, size_t ws_size,
                              hipStream_t stream) {
    const float* x     = (const float*)d_in[0];
    const float* W_in  = (const float*)d_in[1];
    const float* b_in  = (const float*)d_in[2];
    const float* W_s   = (const float*)d_in[3];
    const float* b_s   = (const float*)d_in[4];
    const float* W_out = (const float*)d_in[5];
    const float* b_out = (const float*)d_in[6];
    float* out = (float*)d_out;

    const int B = out_size;                 // [B,1] output
    const int T = in_sizes[0] / B;          // x is [B,T,1]

    const int blocks = B / RPG;             // 256 for B=4096 -> 1024 waves, 1/SIMD
    ssm_kernel<<<blocks, 256, 0, stream>>>(
        x, W_in, b_in, W_s, b_s, W_out, b_out, out, B, T);
}

// Round 7
// 2816.737 us; speedup vs baseline: 2.7188x; 1.1173x over previous
//
#include <hip/hip_runtime.h>
#include <cstdint>
#include <cstddef>

#define HID 64
#define RPG 16          // batch rows per block = one MFMA M-tile
#define HSTR 72         // ushorts per h-plane row: 144 B (16B-aligned, bank-spread)

typedef short bf16x8 __attribute__((ext_vector_type(8)));
typedef float f32x4 __attribute__((ext_vector_type(4)));
typedef float f32x2 __attribute__((ext_vector_type(2)));

// Exact-erf GELU via Abramowitz & Stegun 7.1.26 (max |erf err| ~1.5e-7).
__device__ __forceinline__ float fast_gelu(float z) {
    float u = z * 0.70710678118654752f;
    float a = __builtin_fabsf(u);
    float t = __builtin_amdgcn_rcpf(__builtin_fmaf(0.3275911f, a, 1.0f));
    float e = __builtin_amdgcn_exp2f((u * u) * -1.44269504088896f);   // exp(-u^2)
    float p =                   1.061405429f;
    p = __builtin_fmaf(p, t, -1.453152027f);
    p = __builtin_fmaf(p, t,  1.421413741f);
    p = __builtin_fmaf(p, t, -0.284496736f);
    p = __builtin_fmaf(p, t,  0.254829592f);
    p = p * t;
    float er = __builtin_fmaf(-p, e, 1.0f);
    er = __builtin_copysignf(er, u);
    float zh = 0.5f * z;
    return __builtin_fmaf(zh, er, zh);
}

__device__ __forceinline__ ushort bf16_hi(float f) {
    return (ushort)(__float_as_uint(f) >> 16);
}
__device__ __forceinline__ float bf16_f(ushort u) {
    return __uint_as_float(((unsigned)u) << 16);
}

// One recurrence step. Reads h(t) split-planes via RHI/RLO (loop-invariant
// lane pointers), 6 MFMAs as 3 independent 2-chains, finishes elements E0,E1
// (compile-time!) and writes them to WHI/WLO. One barrier per step.
#define STEP(RHI, RLO, WHI, WLO, E0, E1) { \
    const bf16x8 Ahi0 = *reinterpret_cast<const bf16x8*>(RHI); \
    const bf16x8 Ahi1 = *reinterpret_cast<const bf16x8*>((RHI) + 32); \
    const bf16x8 Alo0 = *reinterpret_cast<const bf16x8*>(RLO); \
    const bf16x8 Alo1 = *reinterpret_cast<const bf16x8*>((RLO) + 32); \
    const f32x2 xr = *reinterpret_cast<const f32x2*>(&xlds[tl][4 * q + E0]); \
    const f32x4 zz = {0.f, 0.f, 0.f, 0.f}; \
    f32x4 ahh = __builtin_amdgcn_mfma_f32_16x16x32_bf16(Ahi0, Bhi0, zz, 0, 0, 0); \
    f32x4 ac1 = __builtin_amdgcn_mfma_f32_16x16x32_bf16(Ahi0, Blo0, zz, 0, 0, 0); \
    f32x4 ac2 = __builtin_amdgcn_mfma_f32_16x16x32_bf16(Alo0, Bhi0, zz, 0, 0, 0); \
    ahh = __builtin_amdgcn_mfma_f32_16x16x32_bf16(Ahi1, Bhi1, ahh, 0, 0, 0); \
    ac1 = __builtin_amdgcn_mfma_f32_16x16x32_bf16(Ahi1, Blo1, ac1, 0, 0, 0); \
    ac2 = __builtin_amdgcn_mfma_f32_16x16x32_bf16(Alo1, Bhi1, ac2, 0, 0, 0); \
    const float z0 = (ahh[E0] + ac1[E0]) + (ac2[E0] + __builtin_fmaf(xr[0], win, cb)); \
    const float z1 = (ahh[E1] + ac1[E1]) + (ac2[E1] + __builtin_fmaf(xr[1], win, cb)); \
    const float h0 = fast_gelu(z0); \
    const float h1 = fast_gelu(z1); \
    const unsigned hb0 = __float_as_uint(h0), hb1 = __float_as_uint(h1); \
    (WHI)[0]    = (ushort)(hb0 >> 16); \
    (WHI)[HSTR] = (ushort)(hb1 >> 16); \
    (WLO)[0]    = bf16_hi(h0 - __uint_as_float(hb0 & 0xffff0000u)); \
    (WLO)[HSTR] = bf16_hi(h1 - __uint_as_float(hb1 & 0xffff0000u)); \
    __syncthreads(); }

// Main loop specialized per element-half so all C-vector indices are literals
// (runtime-indexed ext_vectors go to scratch — rule #20).
#define MAINLOOP(E0, E1) { \
    ushort* const whi1 = &hlds[1][0][(4 * q + E0) * HSTR + c]; \
    ushort* const wlo1 = &hlds[1][1][(4 * q + E0) * HSTR + c]; \
    ushort* const whi0 = &hlds[0][0][(4 * q + E0) * HSTR + c]; \
    ushort* const wlo0 = &hlds[0][1][(4 * q + E0) * HSTR + c]; \
    for (int tc = 0; tc < nch; ++tc) { \
        xlds[lane][ww]     = x[(size_t)(bA + ww) * (size_t)T + (size_t)(tc * 64) + lane]; \
        xlds[lane][ww + 8] = x[(size_t)(bA + ww + 8) * (size_t)T + (size_t)(tc * 64) + lane]; \
        __syncthreads(); \
        _Pragma("unroll 1") \
        for (int tl2 = 0; tl2 < 32; ++tl2) { \
            { const int tl = 2 * tl2;     STEP(rhi0, rlo0, whi1, wlo1, E0, E1) } \
            { const int tl = 2 * tl2 + 1; STEP(rhi1, rlo1, whi0, wlo0, E0, E1) } \
        } \
    } }

__global__ __launch_bounds__(512, 2)
void ssm_kernel(const float* __restrict__ x,
                const float* __restrict__ W_in,
                const float* __restrict__ b_in,
                const float* __restrict__ W_s,
                const float* __restrict__ b_s,
                const float* __restrict__ W_out,
                const float* __restrict__ b_out,
                float* __restrict__ out,
                int B, int T) {
    // h state as split-bf16 planes, ping-pong: hlds[pp][hi/lo][row*HSTR + col]
    __shared__ ushort hlds[2][2][RPG * HSTR];
    __shared__ float  xlds[64][RPG];               // x[t_local][row]

    const int tid  = threadIdx.x;
    const int ww   = tid >> 6;        // wave 0..7
    const int g    = ww & 3;          // col-group: owns cols [16g, 16g+16)
    const int hf   = ww >> 2;         // element-half: finishes C rows 4q+2hf, +2hf+1
    const int lane = tid & 63;
    const int q    = lane >> 4;
    const int rr   = lane & 15;
    const int bA   = blockIdx.x * RPG;
    const int c    = (g << 4) | rr;   // this lane's output column (0..63)

    if (bA >= B) return;

    // B fragments (weights): B[k][c], k = 32*half + 8*q + e, split hi/lo bf16.
    // A-frags below use the SAME k map, so any map error cancels in the sum.
    bf16x8 Bhi0, Bhi1, Blo0, Blo1;
#pragma unroll
    for (int e = 0; e < 8; ++e) {
        {
            const float wf = W_s[(q * 8 + e) * HID + c];
            const ushort hi = bf16_hi(wf);
            Bhi0[e] = (short)hi;
            Blo0[e] = (short)bf16_hi(wf - bf16_f(hi));
        }
        {
            const float wf = W_s[(32 + q * 8 + e) * HID + c];
            const ushort hi = bf16_hi(wf);
            Bhi1[e] = (short)hi;
            Blo1[e] = (short)bf16_hi(wf - bf16_f(hi));
        }
    }
    // Pin in VGPRs (round-1 lesson: const global loads get rematerialized).
    asm volatile("" : "+v"(Bhi0), "+v"(Bhi1), "+v"(Blo0), "+v"(Blo1));

    const float win = W_in[c];
    const float cb  = b_in[c] + b_s[c];

    // zero h(pp=0); the staging barrier below orders it before first read
    {
        ushort* p = &hlds[0][0][0];
        for (int i = tid; i < 2 * RPG * HSTR; i += 512) p[i] = 0;
    }

    // Loop-invariant A-frag read pointers (row rr, k-slice q*8..+8; +32 = half 1)
    const ushort* const rhi0 = &hlds[0][0][rr * HSTR + q * 8];
    const ushort* const rlo0 = &hlds[0][1][rr * HSTR + q * 8];
    const ushort* const rhi1 = &hlds[1][0][rr * HSTR + q * 8];
    const ushort* const rlo1 = &hlds[1][1][rr * HSTR + q * 8];

    const int nch = T >> 6;           // T multiple of 64 (8192 here)

    if (hf == 0) { MAINLOOP(0, 1) } else { MAINLOOP(2, 3) }

    // Epilogue (h final is in hlds[0]; 64*nch steps = even). hf==0 waves only.
    if (hf == 0) {
        const int row = (g << 2) + q;
        const int c4  = rr << 2;
        const ushort* hp = &hlds[0][0][row * HSTR + c4];
        const ushort* lp = &hlds[0][1][row * HSTR + c4];
        float s = 0.f;
#pragma unroll
        for (int j = 0; j < 4; ++j) {
            const float hv = bf16_f(hp[j]) + bf16_f(lp[j]);
            s = __builtin_fmaf(hv, W_out[c4 + j], s);
        }
        s += __shfl_xor(s, 1, 64);
        s += __shfl_xor(s, 2, 64);
        s += __shfl_xor(s, 4, 64);
        s += __shfl_xor(s, 8, 64);
        if (rr == 0) out[bA + row] = s + b_out[0];
    }
}

extern "C" void kernel_launch(void* const* d_in, const int* in_sizes, int n_in,
                              void* d_out, int out_size, void* d_ws, size_t ws_size,
                              hipStream_t stream) {
    const float* x     = (const float*)d_in[0];
    const float* W_in  = (const float*)d_in[1];
    const float* b_in  = (const float*)d_in[2];
    const float* W_s   = (const float*)d_in[3];
    const float* b_s   = (const float*)d_in[4];
    const float* W_out = (const float*)d_in[5];
    const float* b_out = (const float*)d_in[6];
    float* out = (float*)d_out;

    const int B = out_size;                 // [B,1] output
    const int T = in_sizes[0] / B;          // x is [B,T,1]

    const int blocks = B / RPG;             // 256 for B=4096
    ssm_kernel<<<blocks, 512, 0, stream>>>(
        x, W_in, b_in, W_s, b_s, W_out, b_out, out, B, T);
}

// Round 9
// 2641.355 us; speedup vs baseline: 2.8993x; 1.0664x over previous
//
#include <hip/hip_runtime.h>
#include <cstdint>
#include <cstddef>

#define HID 64
#define RPG 16          // batch rows per block = one MFMA N-tile (swapped form)
#define HSTR 72         // ushorts per h row: 144 B (16B-aligned, 2-way banks only)
#define XSTR 68         // floats per x row: 272 B (16B-aligned)

typedef short bf16x8 __attribute__((ext_vector_type(8)));
typedef float f32x4 __attribute__((ext_vector_type(4)));

// Exact-erf GELU via Abramowitz & Stegun 7.1.26 (max |erf err| ~1.5e-7).
__device__ __forceinline__ float fast_gelu(float z) {
    float u = z * 0.70710678118654752f;
    float a = __builtin_fabsf(u);
    float t = __builtin_amdgcn_rcpf(__builtin_fmaf(0.3275911f, a, 1.0f));
    float e = __builtin_amdgcn_exp2f((u * u) * -1.44269504088896f);   // exp(-u^2)
    float p =                   1.061405429f;
    p = __builtin_fmaf(p, t, -1.453152027f);
    p = __builtin_fmaf(p, t,  1.421413741f);
    p = __builtin_fmaf(p, t, -0.284496736f);
    p = __builtin_fmaf(p, t,  0.254829592f);
    p = p * t;
    float er = __builtin_fmaf(-p, e, 1.0f);
    er = __builtin_copysignf(er, u);
    float zh = 0.5f * z;
    return __builtin_fmaf(zh, er, zh);
}

__device__ __forceinline__ ushort bf16_hi(float f) {
    return (ushort)(__float_as_uint(f) >> 16);
}
__device__ __forceinline__ float bf16_f(ushort u) {
    return __uint_as_float(((unsigned)u) << 16);
}

// One step, swapped form: D'[c'][r] = sum_k W^T[c'][k] h[k][r].
// A = W^T (static regs), B = h read [r][k] row-major (b128/plane/K-half).
// C/D: col=lane&15 = r (fixed rr), row = 4q+reg = c-quad -> CONTIGUOUS c.
// This wave finishes elements E0,E1 (compile-time literals, passed through)
// and stores them as ONE packed u32 per plane. One barrier per step.
#define STEP(RHI, RLO, WHI, WLO, XB, E0, E1) { \
    const bf16x8 Hhi0 = *reinterpret_cast<const bf16x8*>(RHI); \
    const bf16x8 Hhi1 = *reinterpret_cast<const bf16x8*>((RHI) + 32); \
    const bf16x8 Hlo0 = *reinterpret_cast<const bf16x8*>(RLO); \
    const bf16x8 Hlo1 = *reinterpret_cast<const bf16x8*>((RLO) + 32); \
    const f32x4 zz = {0.f, 0.f, 0.f, 0.f}; \
    f32x4 ahh = __builtin_amdgcn_mfma_f32_16x16x32_bf16(Whi0, Hhi0, zz, 0, 0, 0); \
    f32x4 ac1 = __builtin_amdgcn_mfma_f32_16x16x32_bf16(Whi0, Hlo0, zz, 0, 0, 0); \
    f32x4 ac2 = __builtin_amdgcn_mfma_f32_16x16x32_bf16(Wlo0, Hhi0, zz, 0, 0, 0); \
    ahh = __builtin_amdgcn_mfma_f32_16x16x32_bf16(Whi1, Hhi1, ahh, 0, 0, 0); \
    ac1 = __builtin_amdgcn_mfma_f32_16x16x32_bf16(Whi1, Hlo1, ac1, 0, 0, 0); \
    ac2 = __builtin_amdgcn_mfma_f32_16x16x32_bf16(Wlo1, Hhi1, ac2, 0, 0, 0); \
    const float z0 = (ahh[E0] + ac1[E0]) + (ac2[E0] + __builtin_fmaf((XB), win0, cb0)); \
    const float z1 = (ahh[E1] + ac1[E1]) + (ac2[E1] + __builtin_fmaf((XB), win1, cb1)); \
    const float h0 = fast_gelu(z0); \
    const float h1 = fast_gelu(z1); \
    const unsigned hb0 = __float_as_uint(h0), hb1 = __float_as_uint(h1); \
    *(WHI) = (hb0 >> 16) | (hb1 & 0xffff0000u); \
    const float l0 = h0 - __uint_as_float(hb0 & 0xffff0000u); \
    const float l1 = h1 - __uint_as_float(hb1 & 0xffff0000u); \
    *(WLO) = (__float_as_uint(l0) >> 16) | (__float_as_uint(l1) & 0xffff0000u); \
    __syncthreads(); }

// Main loop specialized per element-half so all C-vector indices are literals
// (runtime-indexed ext_vectors go to scratch — rule #20). E0/E1 are literal
// tokens here and are substituted into the STEP calls below.
#define MAINLOOP(E0, E1) { \
    const float win0 = W_in[cq + E0]; \
    const float win1 = W_in[cq + E1]; \
    const float cb0  = b_in[cq + E0] + b_s[cq + E0]; \
    const float cb1  = b_in[cq + E1] + b_s[cq + E1]; \
    const ushort* const rhiA = &hlds[0][0][rr * HSTR + 8 * q]; \
    const ushort* const rloA = &hlds[0][1][rr * HSTR + 8 * q]; \
    const ushort* const rhiB = &hlds[1][0][rr * HSTR + 8 * q]; \
    const ushort* const rloB = &hlds[1][1][rr * HSTR + 8 * q]; \
    unsigned* const whiA = reinterpret_cast<unsigned*>(&hlds[0][0][rr * HSTR + cq + E0]); \
    unsigned* const wloA = reinterpret_cast<unsigned*>(&hlds[0][1][rr * HSTR + cq + E0]); \
    unsigned* const whiB = reinterpret_cast<unsigned*>(&hlds[1][0][rr * HSTR + cq + E0]); \
    unsigned* const wloB = reinterpret_cast<unsigned*>(&hlds[1][1][rr * HSTR + cq + E0]); \
    for (int tc = 0; tc < nch; ++tc) { \
        const size_t tg = (size_t)tc * 64; \
        xlds[ww][lane]     = x[(size_t)(bA + ww) * (size_t)T + tg + lane]; \
        xlds[ww + 8][lane] = x[(size_t)(bA + ww + 8) * (size_t)T + tg + lane]; \
        __syncthreads(); \
        _Pragma("unroll 1") \
        for (int t4 = 0; t4 < 16; ++t4) { \
            const f32x4 xq = *reinterpret_cast<const f32x4*>(&xlds[rr][t4 * 4]); \
            STEP(rhiA, rloA, whiB, wloB, xq[0], E0, E1) \
            STEP(rhiB, rloB, whiA, wloA, xq[1], E0, E1) \
            STEP(rhiA, rloA, whiB, wloB, xq[2], E0, E1) \
            STEP(rhiB, rloB, whiA, wloA, xq[3], E0, E1) \
        } \
    } }

__global__ __launch_bounds__(512, 2)
void ssm_kernel(const float* __restrict__ x,
                const float* __restrict__ W_in,
                const float* __restrict__ b_in,
                const float* __restrict__ W_s,
                const float* __restrict__ b_s,
                const float* __restrict__ W_out,
                const float* __restrict__ b_out,
                float* __restrict__ out,
                int B, int T) {
    // h state split-bf16, ping-pong, [r][k] row-major: hlds[pp][hi/lo][r*HSTR + k]
    __shared__ ushort hlds[2][2][RPG * HSTR];
    __shared__ float  xlds[RPG][XSTR];             // x[r][t_local], padded rows

    const int tid  = threadIdx.x;
    const int ww   = tid >> 6;        // wave 0..7
    const int g    = ww & 3;          // c-tile: owns cols [16g, 16g+16)
    const int hf   = ww >> 2;         // element-half: finishes regs {2hf, 2hf+1}
    const int lane = tid & 63;
    const int q    = lane >> 4;
    const int rr   = lane & 15;       // this lane's batch row (C col-index)
    const int bA   = blockIdx.x * RPG;
    const int cq   = 16 * g + 4 * q;  // c-quad base this lane produces

    // A-operand = W^T tile g (static): lane rr holds W^T[c'=rr][k=8q+e] = W_s[k][16g+rr].
    bf16x8 Whi0, Whi1, Wlo0, Wlo1;
    const int wcol = 16 * g + rr;
#pragma unroll
    for (int e = 0; e < 8; ++e) {
        {   const float wf = W_s[(8 * q + e) * HID + wcol];
            const ushort hi = bf16_hi(wf);
            Whi0[e] = (short)hi;
            Wlo0[e] = (short)bf16_hi(wf - bf16_f(hi)); }
        {   const float wf = W_s[(32 + 8 * q + e) * HID + wcol];
            const ushort hi = bf16_hi(wf);
            Whi1[e] = (short)hi;
            Wlo1[e] = (short)bf16_hi(wf - bf16_f(hi)); }
    }
    // Pin in VGPRs (round-1 lesson: const global loads get rematerialized).
    asm volatile("" : "+v"(Whi0), "+v"(Whi1), "+v"(Wlo0), "+v"(Wlo1));

    // zero h(pp=0); ordered before first read by the staging barrier below
    {
        ushort* p = &hlds[0][0][0];
        for (int i = tid; i < 2 * RPG * HSTR; i += 512) p[i] = 0;
    }

    const int nch = T >> 6;           // T multiple of 64 (8192 here)

    if (hf == 0) { MAINLOOP(0, 1) } else { MAINLOOP(2, 3) }

    // Epilogue: h final in hlds[0] (even step count). out[b] = h.W_out + b_out.
    if (ww == 0) {
        const int r  = lane >> 2;
        const int p4 = lane & 3;
        const ushort* hp = &hlds[0][0][r * HSTR + p4 * 16];
        const ushort* lp = &hlds[0][1][r * HSTR + p4 * 16];
        float s = 0.f;
#pragma unroll
        for (int j = 0; j < 16; ++j)
            s = __builtin_fmaf(bf16_f(hp[j]) + bf16_f(lp[j]), W_out[p4 * 16 + j], s);
        s += __shfl_xor(s, 1, 64);
        s += __shfl_xor(s, 2, 64);
        if (p4 == 0) out[bA + r] = s + b_out[0];
    }
}

extern "C" void kernel_launch(void* const* d_in, const int* in_sizes, int n_in,
                              void* d_out, int out_size, void* d_ws, size_t ws_size,
                              hipStream_t stream) {
    const float* x     = (const float*)d_in[0];
    const float* W_in  = (const float*)d_in[1];
    const float* b_in  = (const float*)d_in[2];
    const float* W_s   = (const float*)d_in[3];
    const float* b_s   = (const float*)d_in[4];
    const float* W_out = (const float*)d_in[5];
    const float* b_out = (const float*)d_in[6];
    float* out = (float*)d_out;

    const int B = out_size;                 // [B,1] output
    const int T = in_sizes[0] / B;          // x is [B,T,1]

    const int blocks = B / RPG;             // 256 for B=4096
    ssm_kernel<<<blocks, 512, 0, stream>>>(
        x, W_in, b_in, W_s, b_s, W_out, b_out, out, B, T);
}